// Round 5
// baseline (19.510 us; speedup 1.0000x reference)
//
#include <hip/hip_runtime.h>

// YOLOv2 loss. preds [B,S,S,A,25] f32, labels [B,S,S,25] f32, out scalar f32.
// v5: every global line touched exactly once (float4 label staging, dense
// half-wave record gather into transposed LDS), compute from LDS.
constexpr int kB     = 1024;
constexpr int kS     = 13;
constexpr int kA     = 5;
constexpr int kC5    = 25;
constexpr int kRec   = kA * kC5;           // 125 floats / cell pred record
constexpr int kCells = kB * kS * kS;       // 173056
constexpr int kBlock = 256;                // 4 waves
constexpr int kCPB   = 64;                 // cells per block
constexpr int kNBlk  = kCells / kCPB;      // 2704 exact
constexpr int kSlots = 32;                 // record slots per chunk
constexpr int kTS    = kSlots + 1;         // 33: transposed row stride (floats)
static_assert(kCells % kCPB == 0, "exact tiling");

__global__ __launch_bounds__(kBlock)
void yolo_main(const float* __restrict__ preds,
               const float* __restrict__ labels,
               float* __restrict__ partial)
{
    __shared__ __align__(16) float lab[kCPB * kC5];   // 6400 B
    __shared__ float precT[kRec * kTS];               // 16.5 KB, [m][slot]
    __shared__ unsigned short objIdx[kCPB];
    __shared__ int   nObjS;
    __shared__ float sred[4];

    const int tid  = threadIdx.x;
    const int lane = tid & 63;
    const int wid  = tid >> 6;
    const int hw   = wid * 2 + (lane >> 5);   // half-wave id 0..7
    const int l32  = lane & 31;
    const size_t cellBase = (size_t)blockIdx.x * kCPB;

    // ---- 1) stage labels: 400 float4, each label line fetched exactly once ----
    {
        const float4* __restrict__ src = (const float4*)(labels + cellBase * kC5);
        float4* dst = (float4*)lab;
        dst[tid] = src[tid];
        if (tid < (kCPB * kC5 / 4) - kBlock)    // 400-256 = 144
            dst[kBlock + tid] = src[kBlock + tid];
    }
    __syncthreads();

    // ---- 2) wave 0: ballot-compact the object cells ----
    if (wid == 0) {
        const bool isObj = (lab[lane * kC5 + 4] == 1.0f);
        const unsigned long long bm = __ballot(isObj);
        if (isObj) {
            int pre = __popcll(bm & ((1ull << lane) - 1ull));
            objIdx[pre] = (unsigned short)lane;
        }
        if (lane == 0) nObjS = __popcll(bm);
    }
    __syncthreads();
    const int nObj = nObjS;

    float loss = 0.0f;
    const float* __restrict__ pb = preds + cellBase * kRec;

    for (int c0 = 0; c0 < nObj; c0 += kSlots) {
        const int cn = min(nObj - c0, kSlots);

        // ---- 3) dense gather: half-wave per record, 32-dword bursts ----
        // Each pred line is requested exactly once. LDS transposed:
        // write bank = (l32 + r) % 32 -> 2-way (free); read bank = t+c -> none.
        for (int r = hw; r < cn; r += 8) {
            const float* __restrict__ rec = pb + (int)objIdx[c0 + r] * kRec;
            #pragma unroll
            for (int s = 0; s < 4; ++s) {
                const int m = s * 32 + l32;
                if (m < kRec) precT[m * kTS + r] = rec[m];
            }
        }
        __syncthreads();

        // ---- 4) compute: slot-per-thread on wave 0, all operands in LDS ----
        if (tid < cn) {
            const int lc = objIdx[c0 + tid];
            const float* __restrict__ L = lab + lc * kC5;
            const float lx = L[0], ly = L[1], lw = L[2], lh = L[3];
            const float lx1 = lx - lw * 0.5f, lx2 = lx + lw * 0.5f;
            const float ly1 = ly - lh * 0.5f, ly2 = ly + lh * 0.5f;
            const float larea = lw * lh;

            float iou[kA], conf[kA], bxA[kA], byA[kA], bwA[kA], bhA[kA];
            int best = 0;
            float bestIou = -1.0f;
            #pragma unroll
            for (int a = 0; a < kA; ++a) {
                const float px = precT[(a * kC5 + 0) * kTS + tid];
                const float py = precT[(a * kC5 + 1) * kTS + tid];
                const float pw = precT[(a * kC5 + 2) * kTS + tid];
                const float ph = precT[(a * kC5 + 3) * kTS + tid];
                conf[a] = precT[(a * kC5 + 4) * kTS + tid];
                bxA[a] = px; byA[a] = py; bwA[a] = pw; bhA[a] = ph;
                const float px1 = px - pw * 0.5f, px2 = px + pw * 0.5f;
                const float py1 = py - ph * 0.5f, py2 = py + ph * 0.5f;
                const float iw = fmaxf(fminf(px2, lx2) - fmaxf(px1, lx1), 0.0f);
                const float ih = fmaxf(fminf(py2, ly2) - fmaxf(py1, ly1), 0.0f);
                const float inter = iw * ih;
                const float uni = pw * ph + larea - inter;
                const float v = inter / (uni + 1e-12f);
                iou[a] = v;
                if (v > bestIou) { bestIou = v; best = a; }  // == jnp.argmax
            }

            // xy
            const float dx = lx - bxA[best], dy = ly - byA[best];
            loss += 5.0f * (dx * dx + dy * dy);
            // wh
            const float sw = sqrtf(lw) - sqrtf(bwA[best]);
            const float sh = sqrtf(lh) - sqrtf(bhA[best]);
            loss += sw * sw + sh * sh;
            // obj
            const float dob = bestIou - conf[best];
            loss += dob * dob;
            // cls
            float cls = 0.0f;
            #pragma unroll
            for (int j = 5; j < kC5; ++j) {
                const float d = L[j] - precT[(best * kC5 + j) * kTS + tid];
                cls += d * d;
            }
            loss += cls;
            // noobj
            #pragma unroll
            for (int a = 0; a < kA; ++a) {
                if (a != best && iou[a] < 0.6f) {
                    const float d = iou[a] - conf[a];
                    loss += d * d;
                }
            }
        }
        __syncthreads();   // protect precT before next chunk
    }

    // ---- 5) block reduction -> one partial per block ----
    #pragma unroll
    for (int off = 32; off > 0; off >>= 1)
        loss += __shfl_down(loss, off, 64);
    if (lane == 0) sred[wid] = loss;
    __syncthreads();
    if (tid == 0)
        partial[blockIdx.x] = sred[0] + sred[1] + sred[2] + sred[3];
}

__global__ __launch_bounds__(1024)
void yolo_reduce(const float* __restrict__ partial, float* __restrict__ out)
{
    float s = 0.0f;
    for (int i = threadIdx.x; i < kNBlk; i += 1024)
        s += partial[i];
    #pragma unroll
    for (int off = 32; off > 0; off >>= 1)
        s += __shfl_down(s, off, 64);
    __shared__ float sred[16];
    const int lane = threadIdx.x & 63;
    const int wid  = threadIdx.x >> 6;
    if (lane == 0) sred[wid] = s;
    __syncthreads();
    if (threadIdx.x == 0) {
        float t = 0.0f;
        #pragma unroll
        for (int w = 0; w < 16; ++w) t += sred[w];
        out[0] = t * (1.0f / (float)kB);
    }
}

extern "C" void kernel_launch(void* const* d_in, const int* in_sizes, int n_in,
                              void* d_out, int out_size, void* d_ws, size_t ws_size,
                              hipStream_t stream) {
    const float* preds  = (const float*)d_in[0];
    const float* labels = (const float*)d_in[1];
    float* out     = (float*)d_out;
    float* partial = (float*)d_ws;          // 2704 floats

    yolo_main<<<kNBlk, kBlock, 0, stream>>>(preds, labels, partial);
    yolo_reduce<<<1, 1024, 0, stream>>>(partial, out);
}